// Round 4
// baseline (791.023 us; speedup 1.0000x reference)
//
#include <hip/hip_runtime.h>

// MaxUnpooling2D scatter-add — 16-channel / eighth-plane privatization.
// updates/mask: [32,64,64,128] f32/i32, out: [32,128,128,128] f32.
// out flat = (b<<21) | (bin<<7) | c  where bin = mask>>7 in [0,16384).
//
// R3: float4/int4 granules (4ch/block)             -> 190us
// R4: 32KB LDS for 4 blocks/CU -> VGPR clamp spill -> 600us
// R5: 512thr/8pos, 16 waves/CU, no spill           -> 185us == R3!
//     Occupancy doubling changed NOTHING -> limit is per-request
//     throughput: 16B granules at 512B stride (64 line-txns per wave
//     instr; 16B-masked deposits -> partial-sector HBM write bursts).
// R6: 16 channels/block, sector-complete 64B loads+stores. Right design,
//     but __launch_bounds__(1024,4) clamped VGPRs to 64 (empirical rule
//     across R3-R6: cap = 256/arg, NOT the documented 512/waves-per-eu)
//     -> 96-VGPR cache spilled per-pass (WRITE 350->583MB, 555us).
// R7: identical to R6 with __launch_bounds__(1024,2) -> cap 128, cache
//     fits (R3 proved 96 data VGPRs live spill-free at cap 128).
//     Occupancy stays 16 waves/CU = exactly R5's level, which sufficed.
//
// XCD swizzle: b = bid&31 -> the 8 channel-group partners of a batch share
// bid%8 (same XCD); they jointly cover each 512B input/output line, so L2
// serves one fetch per line and merges 8x64B dirty sectors into full lines.
// 256 blocks = 1/CU exactly; 4 batches x 8 groups per XCD.

#define HWC (64 * 64 * 128)   // 2^19 input elements per batch
#define PBINS 2048            // bins per pass (16 output rows x 128 x)
#define NPASS 8

__global__ __launch_bounds__(1024, 2) void unpool_c16(
    const float* __restrict__ upd, const int* __restrict__ mask,
    float* __restrict__ out)
{
    extern __shared__ float acc[];     // [2048 bins][16 ch] = 128 KiB

    int bid = blockIdx.x;
    int b   = bid & 31;
    int c0  = (bid >> 5) << 4;         // 16-channel group base, 0..112

    int t    = threadIdx.x;
    int quad = t & 3;                  // which float4 within the 16 channels
    int prow = t >> 2;                 // 0..255

    const float* ubase = upd  + (size_t)b * HWC + c0 + quad * 4;
    const int*   mbase = mask + (size_t)b * HWC + c0 + quad * 4;
    float*       obase = out + ((size_t)b << 21) + c0;

    // Register-cache this block's full input: 16 iters, pos = prow + k*256.
    // Lanes 4i..4i+3 read 4 consecutive float4s = one 64B sector/request.
    // u: 64 VGPRs; packed bins: 32 VGPRs (bin < 16384 fits u16).
    float4 u[16];
    uint2  pk[16];
    #pragma unroll
    for (int k = 0; k < 16; ++k) {
        int pos = prow + (k << 8);     // (h,w) position 0..4095
        u[k] = *(const float4*)(ubase + (size_t)pos * 128);
        int4 m4 = *(const int4*)(mbase + (size_t)pos * 128);
        unsigned b0 = ((unsigned)m4.x) >> 7;
        unsigned b1 = ((unsigned)m4.y) >> 7;
        unsigned b2 = ((unsigned)m4.z) >> 7;
        unsigned b3 = ((unsigned)m4.w) >> 7;
        pk[k].x = b0 | (b1 << 16);
        pk[k].y = b2 | (b3 << 16);
    }

    float4* a4 = (float4*)acc;         // 8192 float4

    int cbase = quad << 2;             // this thread's channel offset 0/4/8/12

    for (int q = 0; q < NPASS; ++q) {
        // zero 128 KiB (8 float4 per thread, contiguous)
        #pragma unroll
        for (int k = 0; k < 8; ++k)
            a4[t + k * 1024] = make_float4(0.f, 0.f, 0.f, 0.f);
        __syncthreads();

        // scatter this pass's elements into LDS (ds_add, no return)
        unsigned uq = (unsigned)q;
        #pragma unroll
        for (int k = 0; k < 16; ++k) {
            unsigned b0 = pk[k].x & 0xffffu;
            unsigned b1 = pk[k].x >> 16;
            unsigned b2 = pk[k].y & 0xffffu;
            unsigned b3 = pk[k].y >> 16;
            if ((b0 >> 11) == uq) atomicAdd(&acc[((b0 & 2047u) << 4) + cbase + 0], u[k].x);
            if ((b1 >> 11) == uq) atomicAdd(&acc[((b1 & 2047u) << 4) + cbase + 1], u[k].y);
            if ((b2 >> 11) == uq) atomicAdd(&acc[((b2 & 2047u) << 4) + cbase + 2], u[k].z);
            if ((b3 >> 11) == uq) atomicAdd(&acc[((b3 & 2047u) << 4) + cbase + 3], u[k].w);
        }
        __syncthreads();

        // store the pass: lanes 4i..4i+3 cover one bin's 64B sector.
        // idx = bin*4 + quad'; out[b, q*2048+bin, c0 + quad'*4 .. +4]
        #pragma unroll
        for (int k = 0; k < 8; ++k) {
            int idx = t + k * 1024;
            int bin = idx >> 2;
            int qd  = idx & 3;
            *(float4*)(obase + (size_t)(q * PBINS + bin) * 128 + qd * 4) = a4[idx];
        }
        if (q < NPASS - 1) __syncthreads();   // next pass rewrites acc
    }
}

extern "C" void kernel_launch(void* const* d_in, const int* in_sizes, int n_in,
                              void* d_out, int out_size, void* d_ws, size_t ws_size,
                              hipStream_t stream) {
    const float* upd  = (const float*)d_in[0];
    const int*   mask = (const int*)d_in[1];
    float*       out  = (float*)d_out;

    // 128 KiB dynamic LDS needs the opt-in attribute (host-side, set once;
    // not a stream op -> graph-capture safe).
    static bool lds_ok = false;
    if (!lds_ok) {
        hipFuncSetAttribute((const void*)unpool_c16,
                            hipFuncAttributeMaxDynamicSharedMemorySize,
                            PBINS * 16 * 4);
        lds_ok = true;
    }

    // 32 batches x 8 channel-groups; every output element written exactly
    // once -> no memset, no global atomics.
    unpool_c16<<<256, 1024, PBINS * 16 * 4, stream>>>(upd, mask, out);
}

// Round 5
// 778.033 us; speedup vs baseline: 1.0167x; 1.0167x over previous
//
#include <hip/hip_runtime.h>

// MaxUnpooling2D scatter-add — 16-channel / eighth-plane privatization.
// updates/mask: [32,64,64,128] f32/i32, out: [32,128,128,128] f32.
// out flat = (b<<21) | (bin<<7) | c  where bin = mask>>7 in [0,16384).
//
// R3: float4/int4 granules (4ch/block)             -> 190us
// R4: 32KB LDS for 4 blocks/CU -> VGPR clamp spill -> 600us
// R5: 512thr/8pos, 16 waves/CU, no spill           -> 185us == R3!
//     Occupancy doubling changed NOTHING -> limit is per-request
//     throughput: 16B granules at 512B stride (64 line-txns per wave
//     instr; 16B-masked deposits -> partial-sector HBM write bursts).
// R6/R7: 16 channels/block, sector-complete 64B loads+stores. Right
//     design, but the 96-VGPR register cache spilled BOTH times:
//     empirically __launch_bounds__'s 2nd arg acts like CUDA's
//     minBlocksPerMultiprocessor, and VGPR cap = 512 / waves_per_SIMD:
//       (256,2)=2/SIMD->256cap ok | (512,4)=8/SIMD->64 | (1024,2)=8/SIMD->64!
// R8: __launch_bounds__(1024, 1): 16 waves/CU = 4 waves/SIMD -> cap 128.
//     1 block/CU is forced by 128 KiB LDS anyway, so nothing is given up.
//     R3 proved 96 data VGPRs live spill-free under a 128 cap.
//
// XCD swizzle: b = bid&31 -> the 8 channel-group partners of a batch share
// bid%8 (same XCD); they jointly cover each 512B input/output line, so L2
// serves one fetch per line and merges 8x64B dirty sectors into full lines.
// 256 blocks = 1/CU exactly; 4 batches x 8 groups per XCD.

#define HWC (64 * 64 * 128)   // 2^19 input elements per batch
#define PBINS 2048            // bins per pass (16 output rows x 128 x)
#define NPASS 8

__global__ __launch_bounds__(1024, 1) void unpool_c16(
    const float* __restrict__ upd, const int* __restrict__ mask,
    float* __restrict__ out)
{
    extern __shared__ float acc[];     // [2048 bins][16 ch] = 128 KiB

    int bid = blockIdx.x;
    int b   = bid & 31;
    int c0  = (bid >> 5) << 4;         // 16-channel group base, 0..112

    int t    = threadIdx.x;
    int quad = t & 3;                  // which float4 within the 16 channels
    int prow = t >> 2;                 // 0..255

    const float* ubase = upd  + (size_t)b * HWC + c0 + quad * 4;
    const int*   mbase = mask + (size_t)b * HWC + c0 + quad * 4;
    float*       obase = out + ((size_t)b << 21) + c0;

    // Register-cache this block's full input: 16 iters, pos = prow + k*256.
    // Lanes 4i..4i+3 read 4 consecutive float4s = one 64B sector/request.
    // u: 64 VGPRs; packed bins: 32 VGPRs (bin = mask>>7 < 16384 fits u16).
    float4 u[16];
    uint2  pk[16];
    #pragma unroll
    for (int k = 0; k < 16; ++k) {
        int pos = prow + (k << 8);     // (h,w) position 0..4095
        u[k] = *(const float4*)(ubase + (size_t)pos * 128);
        int4 m4 = *(const int4*)(mbase + (size_t)pos * 128);
        unsigned b0 = ((unsigned)m4.x) >> 7;
        unsigned b1 = ((unsigned)m4.y) >> 7;
        unsigned b2 = ((unsigned)m4.z) >> 7;
        unsigned b3 = ((unsigned)m4.w) >> 7;
        pk[k].x = b0 | (b1 << 16);
        pk[k].y = b2 | (b3 << 16);
    }

    float4* a4 = (float4*)acc;         // 8192 float4

    int cbase = quad << 2;             // this thread's channel offset 0/4/8/12

    for (int q = 0; q < NPASS; ++q) {
        // zero 128 KiB (8 float4 per thread, contiguous)
        #pragma unroll
        for (int k = 0; k < 8; ++k)
            a4[t + k * 1024] = make_float4(0.f, 0.f, 0.f, 0.f);
        __syncthreads();

        // scatter this pass's elements into LDS (ds_add, no return)
        unsigned uq = (unsigned)q;
        #pragma unroll
        for (int k = 0; k < 16; ++k) {
            unsigned b0 = pk[k].x & 0xffffu;
            unsigned b1 = pk[k].x >> 16;
            unsigned b2 = pk[k].y & 0xffffu;
            unsigned b3 = pk[k].y >> 16;
            if ((b0 >> 11) == uq) atomicAdd(&acc[((b0 & 2047u) << 4) + cbase + 0], u[k].x);
            if ((b1 >> 11) == uq) atomicAdd(&acc[((b1 & 2047u) << 4) + cbase + 1], u[k].y);
            if ((b2 >> 11) == uq) atomicAdd(&acc[((b2 & 2047u) << 4) + cbase + 2], u[k].z);
            if ((b3 >> 11) == uq) atomicAdd(&acc[((b3 & 2047u) << 4) + cbase + 3], u[k].w);
        }
        __syncthreads();

        // store the pass: lanes 4i..4i+3 cover one bin's 64B sector.
        // idx = bin*4 + quad'; out[b, q*2048+bin, c0 + quad'*4 .. +4]
        #pragma unroll
        for (int k = 0; k < 8; ++k) {
            int idx = t + k * 1024;
            int bin = idx >> 2;
            int qd  = idx & 3;
            *(float4*)(obase + (size_t)(q * PBINS + bin) * 128 + qd * 4) = a4[idx];
        }
        if (q < NPASS - 1) __syncthreads();   // next pass rewrites acc
    }
}

extern "C" void kernel_launch(void* const* d_in, const int* in_sizes, int n_in,
                              void* d_out, int out_size, void* d_ws, size_t ws_size,
                              hipStream_t stream) {
    const float* upd  = (const float*)d_in[0];
    const int*   mask = (const int*)d_in[1];
    float*       out  = (float*)d_out;

    // 128 KiB dynamic LDS needs the opt-in attribute (host-side, set once;
    // not a stream op -> graph-capture safe).
    static bool lds_ok = false;
    if (!lds_ok) {
        hipFuncSetAttribute((const void*)unpool_c16,
                            hipFuncAttributeMaxDynamicSharedMemorySize,
                            PBINS * 16 * 4);
        lds_ok = true;
    }

    // 32 batches x 8 channel-groups; every output element written exactly
    // once -> no memset, no global atomics.
    unpool_c16<<<256, 1024, PBINS * 16 * 4, stream>>>(upd, mask, out);
}

// Round 6
// 443.971 us; speedup vs baseline: 1.7817x; 1.7524x over previous
//
#include <hip/hip_runtime.h>

// MaxUnpooling2D scatter-add — 8-channel / quarter-bin privatization.
// updates/mask: [32,64,64,128] f32/i32, out: [32,128,128,128] f32.
// out flat = (b<<21) | (bin<<7) | c  where bin = mask>>7 in [0,16384).
//
// R3:  4ch/block, float4 granules, 128 VGPR @ 256thr -> 190us
// R4:  spill (VGPR clamp)                             -> 600us
// R5:  512thr/8pos, 48-VGPR cache fits in 64          -> 185us == R3!
//      Occupancy doubling changed nothing -> limit is request
//      granularity/rate, not latency hiding.
// R6-R8: 16ch/block sector-complete design. BLOCKED: for 512/1024-thread
//      blocks hipcc regalloc lands at 64 VGPRs regardless of
//      __launch_bounds__ ((512,4),(1024,2),(1024,1) all -> 64), so the
//      96-VGPR register cache spills (FETCH 67->677MB, 565us). Only
//      256-thread blocks ever got 128. Stop fighting the allocator.
// R9:  8ch/block — the widest channel group whose register cache is
//      exactly R5's proven 48 VGPRs (u[8] float4 + pk[8] uint2):
//      * loads:  lane pairs (t&1) cover 32B of each 64B sector/instr
//                -> 2x fewer load line-requests than R5;
//      * stores: both 16B halves of a bin's 32B written by adjacent
//                lanes in the SAME instruction -> one 32B request/bin,
//                2x fewer store requests; the other sector half comes
//                from partner block bid+32 on the SAME XCD;
//      * LDS [4096 bins][8ch] = 128 KiB dynamic -> NPASS=4 (half the
//                barrier rounds of c16), 1024 thr = 16 waves/CU (R5
//                proved sufficient).
//
// XCD swizzle: b = bid&31 -> all 16 channel-group partners of a batch
// share bid%8 (same XCD); they jointly cover each 512B output line, so
// L2 merges 16x32B dirty chunks into full lines before eviction.
// 512 blocks = 2 rounds of 1/CU; second round keeps the same XCD map.

#define HWC (64 * 64 * 128)   // 2^19 input elements per batch
#define PBINS 4096            // bins per pass (32 output rows x 128 x)
#define NPASS 4

__global__ __launch_bounds__(1024) void unpool_c8(
    const float* __restrict__ upd, const int* __restrict__ mask,
    float* __restrict__ out)
{
    extern __shared__ float acc[];     // [4096 bins][8 ch] = 128 KiB

    int bid = blockIdx.x;
    int b   = bid & 31;
    int c0  = (bid >> 5) << 3;         // 8-channel group base, 0..120

    int t    = threadIdx.x;
    int q    = t & 1;                  // which float4 (quad) within 8 ch
    int prow = t >> 1;                 // 0..511

    const float* ubase = upd  + (size_t)b * HWC + c0 + q * 4;
    const int*   mbase = mask + (size_t)b * HWC + c0 + q * 4;
    float*       obase = out + ((size_t)b << 21) + c0;

    // Register-cache this block's full input slice: 8 items/thread,
    // item = (pos, quad). u: 32 VGPRs; pk: 16 VGPRs (bin < 16384 -> u16).
    // Total 48 data VGPRs — R5-proven to fit the 64-VGPR codegen.
    float4 u[8];
    uint2  pk[8];
    #pragma unroll
    for (int k = 0; k < 8; ++k) {
        int pos = prow + (k << 9);     // (h,w) position 0..4095
        u[k] = *(const float4*)(ubase + (size_t)pos * 128);
        int4 m4 = *(const int4*)(mbase + (size_t)pos * 128);
        unsigned b0 = ((unsigned)m4.x) >> 7;
        unsigned b1 = ((unsigned)m4.y) >> 7;
        unsigned b2 = ((unsigned)m4.z) >> 7;
        unsigned b3 = ((unsigned)m4.w) >> 7;
        pk[k].x = b0 | (b1 << 16);
        pk[k].y = b2 | (b3 << 16);
    }

    float4* a4 = (float4*)acc;         // 8192 float4

    int cbase = q << 2;                // this thread's channel offset 0/4

    for (int p = 0; p < NPASS; ++p) {
        // zero 128 KiB (8 float4 per thread, contiguous)
        #pragma unroll
        for (int k = 0; k < 8; ++k)
            a4[t + k * 1024] = make_float4(0.f, 0.f, 0.f, 0.f);
        __syncthreads();

        // scatter this pass's elements into LDS (ds_add, no return)
        unsigned up = (unsigned)p;
        #pragma unroll
        for (int k = 0; k < 8; ++k) {
            unsigned b0 = pk[k].x & 0xffffu;
            unsigned b1 = pk[k].x >> 16;
            unsigned b2 = pk[k].y & 0xffffu;
            unsigned b3 = pk[k].y >> 16;
            if ((b0 >> 12) == up) atomicAdd(&acc[((b0 & 4095u) << 3) + cbase + 0], u[k].x);
            if ((b1 >> 12) == up) atomicAdd(&acc[((b1 & 4095u) << 3) + cbase + 1], u[k].y);
            if ((b2 >> 12) == up) atomicAdd(&acc[((b2 & 4095u) << 3) + cbase + 2], u[k].z);
            if ((b3 >> 12) == up) atomicAdd(&acc[((b3 & 4095u) << 3) + cbase + 3], u[k].w);
        }
        __syncthreads();

        // store the pass: adjacent lanes (qd=0,1) cover one bin's 32B —
        // single 32B request/bin; partner block bid+32 supplies the other
        // 32B of the 64B sector on the same XCD.
        #pragma unroll
        for (int k = 0; k < 8; ++k) {
            int idx = t + k * 1024;
            int bin = idx >> 1;
            int qd  = idx & 1;
            *(float4*)(obase + (size_t)(p * PBINS + bin) * 128 + qd * 4) = a4[idx];
        }
        if (p < NPASS - 1) __syncthreads();   // next pass rewrites acc
    }
}

extern "C" void kernel_launch(void* const* d_in, const int* in_sizes, int n_in,
                              void* d_out, int out_size, void* d_ws, size_t ws_size,
                              hipStream_t stream) {
    const float* upd  = (const float*)d_in[0];
    const int*   mask = (const int*)d_in[1];
    float*       out  = (float*)d_out;

    // 128 KiB dynamic LDS needs the opt-in attribute (host-side, set once;
    // not a stream op -> graph-capture safe).
    static bool lds_ok = false;
    if (!lds_ok) {
        hipFuncSetAttribute((const void*)unpool_c8,
                            hipFuncAttributeMaxDynamicSharedMemorySize,
                            PBINS * 8 * 4);
        lds_ok = true;
    }

    // 32 batches x 16 channel-groups; every output element written exactly
    // once -> no memset, no global atomics.
    unpool_c8<<<512, 1024, PBINS * 8 * 4, stream>>>(upd, mask, out);
}

// Round 7
// 437.898 us; speedup vs baseline: 1.8064x; 1.0139x over previous
//
#include <hip/hip_runtime.h>

// MaxUnpooling2D scatter-add — 8ch/block, double-buffered LDS, non-draining
// barriers. updates/mask: [32,64,64,128] f32/i32, out: [32,128,128,128] f32.
// out flat = (b<<21) | (bin<<7) | c  where bin = mask>>7 in [0,16384).
//
// R3/R5/R9 all = 185us despite 16B->32B granules, 8->16 waves/CU, 1.3x->1.0x
// write amplification: time is invariant to granularity, occupancy, AND hbm
// bytes. VALUBusy 4.5% -> waves wait 95% of the time. The invariant is the
// phase structure: every pass ends in __syncthreads, which emits
// s_waitcnt vmcnt(0) (guide §5) -> ALL global stores drain to completion
// while every wave idles. 8 forced LDS generations (256MB out / 32MB LDS)
// x serialized {load | store-drain} phases ~= 150-190us. All prior nulls
// explained: co-resident blocks were phase-locked, splitting BW within the
// same phase instead of overlapping phases.
//
// R10: break the drain (HK-proven: memory ops stay in flight across raw
// s_barrier; only lgkmcnt is needed for LDS visibility):
//  * double-buffer: 2 x [1024 bins][8 ch] = 64 KiB. Pass p stores from buf
//    A while pass p+1 zeros/scatters buf B -> no LDS WAR -> NO barrier and
//    NO vmcnt drain after the store phase. Store->VGPR-reuse hazard is
//    handled by compiler-counted vmcnt, one pass deep.
//  * loop barriers = "s_waitcnt lgkmcnt(0); s_barrier" only.
//  * 64 KiB -> 2 blocks/CU (32 waves); un-drained blocks de-phase, mixing
//    one block's loads with the other's stores (full-duplex HBM).
//  * cost: 16 predicated scans (VALU 4.5%@4 -> ~18% worst case, not binding).
//
// Safety: buf A's store-reads are lgkm-drained by each wave at the next
// LGKM_BAR; buf A is next written two passes later (after 2 barriers) ->
// no LDS race. Cross-wave atomic visibility: every wave does lgkmcnt(0)
// before each barrier. Store granule 32B (lane pairs), partner merge in L2
// unchanged from R9 (WRITE was ideal 264MB).

#define HWC (64 * 64 * 128)   // 2^19 input elements per batch
#define PBINS 1024            // bins per pass (8 output rows x 128 x)
#define NPASS 16

#define LGKM_BAR() do { \
    __asm__ __volatile__("s_waitcnt lgkmcnt(0)" ::: "memory"); \
    __builtin_amdgcn_s_barrier(); \
} while (0)

__global__ __launch_bounds__(1024) void unpool_db(
    const float* __restrict__ upd, const int* __restrict__ mask,
    float* __restrict__ out)
{
    extern __shared__ float acc[];     // 2 x [1024 bins][8 ch] = 64 KiB

    int bid = blockIdx.x;
    int b   = bid & 31;
    int c0  = (bid >> 5) << 3;         // 8-channel group base, 0..120

    int t    = threadIdx.x;
    int q    = t & 1;                  // which float4 (quad) within 8 ch
    int prow = t >> 1;                 // 0..511

    const float* ubase = upd  + (size_t)b * HWC + c0 + q * 4;
    const int*   mbase = mask + (size_t)b * HWC + c0 + q * 4;
    float*       obase = out + ((size_t)b << 21) + c0;

    // Register-cache this block's full input slice: 8 items/thread,
    // item = (pos, quad). 48 data VGPRs — R5/R9-proven to fit 64-VGPR codegen.
    float4 u[8];
    uint2  pk[8];
    #pragma unroll
    for (int k = 0; k < 8; ++k) {
        int pos = prow + (k << 9);     // (h,w) position 0..4095
        u[k] = *(const float4*)(ubase + (size_t)pos * 128);
        int4 m4 = *(const int4*)(mbase + (size_t)pos * 128);
        unsigned b0 = ((unsigned)m4.x) >> 7;
        unsigned b1 = ((unsigned)m4.y) >> 7;
        unsigned b2 = ((unsigned)m4.z) >> 7;
        unsigned b3 = ((unsigned)m4.w) >> 7;
        pk[k].x = b0 | (b1 << 16);
        pk[k].y = b2 | (b3 << 16);
    }

    int cbase = q << 2;                // this thread's channel offset 0/4

    for (int p = 0; p < NPASS; ++p) {
        float*  A  = acc + ((p & 1) << 13);   // buffer: 8192 floats each
        float4* a4 = (float4*)A;

        // zero 32 KiB (2 float4 per thread)
        a4[t]        = make_float4(0.f, 0.f, 0.f, 0.f);
        a4[t + 1024] = make_float4(0.f, 0.f, 0.f, 0.f);
        LGKM_BAR();                    // zeros visible; stores still in flight

        // scatter this pass's elements into LDS (ds_add, no return)
        unsigned up = (unsigned)p;
        #pragma unroll
        for (int k = 0; k < 8; ++k) {
            unsigned b0 = pk[k].x & 0xffffu;
            unsigned b1 = pk[k].x >> 16;
            unsigned b2 = pk[k].y & 0xffffu;
            unsigned b3 = pk[k].y >> 16;
            if ((b0 >> 10) == up) atomicAdd(&A[((b0 & 1023u) << 3) + cbase + 0], u[k].x);
            if ((b1 >> 10) == up) atomicAdd(&A[((b1 & 1023u) << 3) + cbase + 1], u[k].y);
            if ((b2 >> 10) == up) atomicAdd(&A[((b2 & 1023u) << 3) + cbase + 2], u[k].z);
            if ((b3 >> 10) == up) atomicAdd(&A[((b3 & 1023u) << 3) + cbase + 3], u[k].w);
        }
        LGKM_BAR();                    // atomics visible to all waves

        // store the pass: adjacent lanes (qd=0,1) cover one bin's 32B.
        // NO barrier, NO vmcnt drain after: next pass uses the other buffer.
        #pragma unroll
        for (int k = 0; k < 2; ++k) {
            int idx = t + (k << 10);
            int bin = idx >> 1;
            int qd  = idx & 1;
            *(float4*)(obase + (size_t)(p * PBINS + bin) * 128 + qd * 4) = a4[idx];
        }
    }
}

extern "C" void kernel_launch(void* const* d_in, const int* in_sizes, int n_in,
                              void* d_out, int out_size, void* d_ws, size_t ws_size,
                              hipStream_t stream) {
    const float* upd  = (const float*)d_in[0];
    const int*   mask = (const int*)d_in[1];
    float*       out  = (float*)d_out;

    // 64 KiB dynamic LDS (at the default cap; attribute set for safety —
    // host-side, once, not a stream op -> graph-capture safe).
    static bool lds_ok = false;
    if (!lds_ok) {
        hipFuncSetAttribute((const void*)unpool_db,
                            hipFuncAttributeMaxDynamicSharedMemorySize,
                            2 * PBINS * 8 * 4);
        lds_ok = true;
    }

    // 32 batches x 16 channel-groups; every output element written exactly
    // once -> no memset, no global atomics.
    unpool_db<<<512, 1024, 2 * PBINS * 8 * 4, stream>>>(upd, mask, out);
}